// Round 1
// baseline (588.280 us; speedup 1.0000x reference)
//
#include <hip/hip_runtime.h>
#include <math.h>

#define LN_EPS_ 1e-5f
#define INV_SQRT_DHEAD 0.17677669529663687f  // 1/sqrt(32)

// B=4, A=16, N=8, L=512, DE=256, DH=64, H=8, DHEAD=32, NL=4096

// ---------------------------------------------------------------------------
// Kernel 1: per (b,a): q = LN(curr_rho) @ Wq.T ; qk[h,e] = sum_dh q[h*32+dh]*Wk[h*32+dh,e]
// g[b,a,h,e] = ln_k_w[e]*qk ; s0 = sum_e g ; s2 = sum_e ln_k_b[e]*qk
// ---------------------------------------------------------------------------
__global__ __launch_bounds__(256) void k_prep(
    const float* __restrict__ curr_rho, const float* __restrict__ Wq,
    const float* __restrict__ Wk, const float* __restrict__ lnqw,
    const float* __restrict__ lnqb, const float* __restrict__ lnkw,
    const float* __restrict__ lnkb,
    float* __restrict__ g, float* __restrict__ s0, float* __restrict__ s2)
{
    __shared__ float xs[256];
    __shared__ float qs[256];
    __shared__ float red[256];
    __shared__ float red2[256];
    const int t = threadIdx.x;
    const int ba = blockIdx.x;  // b*16+a
    const float x = curr_rho[(size_t)ba * 256 + t];

    red[t] = x; __syncthreads();
    for (int s = 128; s > 0; s >>= 1) { if (t < s) red[t] += red[t + s]; __syncthreads(); }
    const float mu = red[0] * (1.0f / 256.0f);
    __syncthreads();
    const float dx = x - mu;
    red[t] = dx * dx; __syncthreads();
    for (int s = 128; s > 0; s >>= 1) { if (t < s) red[t] += red[t + s]; __syncthreads(); }
    const float var = red[0] * (1.0f / 256.0f);
    const float rstd = 1.0f / sqrtf(var + LN_EPS_);
    __syncthreads();
    xs[t] = dx * rstd * lnqw[t] + lnqb[t];
    __syncthreads();

    // q[t] = dot(xs, Wq[t,:])
    {
        const float4* wq4 = (const float4*)(Wq + (size_t)t * 256);
        float acc = 0.f;
        #pragma unroll 8
        for (int e4 = 0; e4 < 64; ++e4) {
            float4 w = wq4[e4];
            acc += xs[e4*4+0]*w.x + xs[e4*4+1]*w.y + xs[e4*4+2]*w.z + xs[e4*4+3]*w.w;
        }
        qs[t] = acc;
    }
    __syncthreads();

    for (int h = 0; h < 8; ++h) {
        float qk = 0.f;
        #pragma unroll 8
        for (int dh = 0; dh < 32; ++dh)
            qk += qs[h*32+dh] * Wk[(size_t)(h*32+dh)*256 + t];
        const float gv = lnkw[t] * qk;
        g[((size_t)ba * 8 + h) * 256 + t] = gv;
        red[t] = gv; red2[t] = lnkb[t] * qk;
        __syncthreads();
        for (int s = 128; s > 0; s >>= 1) {
            if (t < s) { red[t] += red[t+s]; red2[t] += red2[t+s]; }
            __syncthreads();
        }
        if (t == 0) { s0[ba*8+h] = red[0]; s2[ba*8+h] = red2[0]; }
        __syncthreads();
    }
}

// ---------------------------------------------------------------------------
// Kernel 2: vals_tan0 = logmap0(demo_hyp)  (rows of 64)
// ---------------------------------------------------------------------------
__global__ __launch_bounds__(256) void k_vals(
    const float* __restrict__ demo_hyp, float* __restrict__ vals)
{
    __shared__ float red[256];
    const int t = threadIdx.x;
    const size_t base = (size_t)blockIdx.x * 256;
    const float x = demo_hyp[base + t];
    const int w = t >> 6, d = t & 63;
    red[t] = x * x;
    __syncthreads();
    for (int s = 32; s > 0; s >>= 1) { if (d < s) red[w*64+d] += red[w*64+d+s]; __syncthreads(); }
    const float nrm = sqrtf(red[w*64]);
    const float n = fmaxf(nrm, 1e-15f);
    const float u = fminf(n, 1.0f - 1e-5f);
    const float f = atanhf(u) / n;
    vals[base + t] = x * f;
}

// ---------------------------------------------------------------------------
// Kernel 3 (the streamer): scores[b,h,a,n,l] = (rstd*(S1 - mu*s0) + s2)/sqrt(32)
// Block = (b, a, n, 128 l's). 256 thr: 8 rows/pass x 32 lanes/row x 8 cols.
// x and g stay in registers; only 10 partials/lane/row hit LDS.
// ---------------------------------------------------------------------------
__global__ __launch_bounds__(256) void k_scores(
    const float* __restrict__ demo_rho, const int* __restrict__ demo_mask,
    const float* __restrict__ g, const float* __restrict__ s0,
    const float* __restrict__ s2, float* __restrict__ attn)
{
    __shared__ float part[8 * 33 * 13];   // [row][lane(+pad)][val], stride 13: conflict-free
    __shared__ float stats[8][2];
    __shared__ float sbuf[8][128];
    const int t = threadIdx.x;
    const int gid = blockIdx.x;
    const int lc = gid & 3;
    const int n  = (gid >> 2) & 7;
    const int a  = (gid >> 5) & 15;
    const int b  = gid >> 9;
    const int c  = t & 31;   // column group (8 floats each)
    const int r  = t >> 5;   // row within pass

    // g fragments -> registers (64 floats/lane)
    float gr[8][8];
    {
        const float* gb = g + ((size_t)(b*16 + a) * 8) * 256 + c * 8;
        #pragma unroll
        for (int h = 0; h < 8; ++h) {
            float4 ga = *(const float4*)(gb + h * 256);
            float4 gc = *(const float4*)(gb + h * 256 + 4);
            gr[h][0]=ga.x; gr[h][1]=ga.y; gr[h][2]=ga.z; gr[h][3]=ga.w;
            gr[h][4]=gc.x; gr[h][5]=gc.y; gr[h][6]=gc.z; gr[h][7]=gc.w;
        }
    }
    const int r2 = t / 10;
    const int v  = t - r2 * 10;
    float s0v = 0.f, s2v = 0.f;
    if (t < 80 && v < 8) {
        s0v = s0[(b*16 + a) * 8 + v];
        s2v = s2[(b*16 + a) * 8 + v];
    }

    const float* xbase = demo_rho +
        ((size_t)((b*8 + n) * 512 + lc * 128) * 16 + a) * 256 + c * 8;

    for (int p = 0; p < 16; ++p) {
        const int lloc = p * 8 + r;
        const float* xp = xbase + (size_t)lloc * 4096;  // row stride = A*DE
        float4 xa = *(const float4*)(xp);
        float4 xb = *(const float4*)(xp + 4);
        float xv[8] = {xa.x, xa.y, xa.z, xa.w, xb.x, xb.y, xb.z, xb.w};
        float sm = 0.f, sq = 0.f;
        #pragma unroll
        for (int j = 0; j < 8; ++j) { sm += xv[j]; sq += xv[j] * xv[j]; }
        float* pw = part + (r * 33 + c) * 13;
        #pragma unroll
        for (int h = 0; h < 8; ++h) {
            float acc = 0.f;
            #pragma unroll
            for (int j = 0; j < 8; ++j) acc += xv[j] * gr[h][j];
            pw[h] = acc;
        }
        pw[8] = sm; pw[9] = sq;
        __syncthreads();

        float S1 = 0.f;
        if (t < 80) {
            const float* pr = part + (r2 * 33) * 13 + v;
            float acc = 0.f;
            #pragma unroll 8
            for (int cc = 0; cc < 32; ++cc) acc += pr[cc * 13];
            if (v == 8)      stats[r2][0] = acc;
            else if (v == 9) stats[r2][1] = acc;
            else             S1 = acc;
        }
        __syncthreads();

        if (t < 80 && v < 8) {
            const float mu   = stats[r2][0] * (1.0f / 256.0f);
            const float var  = stats[r2][1] * (1.0f / 256.0f) - mu * mu;
            const float rstd = 1.0f / sqrtf(var + LN_EPS_);
            float sc = (rstd * (S1 - mu * s0v) + s2v) * INV_SQRT_DHEAD;
            const int l = lc * 128 + p * 8 + r2;
            if (demo_mask[(b*8 + n) * 512 + l] == 0) sc = -INFINITY;
            sbuf[v][p * 8 + r2] = sc;
        }
    }
    __syncthreads();
    // coalesced write of the 8x128 score tile
    {
        const int h = t >> 5;
        float4 vout = ((const float4*)(&sbuf[h][0]))[c];
        const size_t off = (size_t)((b*8 + h) * 16 + a) * 4096 + n * 512 + lc * 128 + c * 4;
        *(float4*)(attn + off) = vout;
    }
}

// ---------------------------------------------------------------------------
// Kernel 4: softmax over 4096 per (b,h,a) row (2 rows/block) + m_h = attn @ vals
// ---------------------------------------------------------------------------
__global__ __launch_bounds__(256) void k_softmax_mh(
    float* __restrict__ attn, const float* __restrict__ vals,
    float* __restrict__ mh)
{
    __shared__ float p0[4096];
    __shared__ float p1[4096];
    __shared__ float red[256];
    __shared__ float mpart[4][64];
    const int t = threadIdx.x;
    const int row0 = blockIdx.x * 2;
    const int b = row0 >> 7;

    for (int rr = 0; rr < 2; ++rr) {
        const int row = row0 + rr;
        float* dst = attn + (size_t)row * 4096;
        float* pl = rr ? p1 : p0;
        float lmax = -INFINITY;
        float4 v4[4];
        #pragma unroll
        for (int k = 0; k < 4; ++k) {
            float4 vv = ((const float4*)dst)[k * 256 + t];
            v4[k] = vv;
            lmax = fmaxf(lmax, fmaxf(fmaxf(vv.x, vv.y), fmaxf(vv.z, vv.w)));
        }
        red[t] = lmax; __syncthreads();
        for (int s = 128; s > 0; s >>= 1) { if (t < s) red[t] = fmaxf(red[t], red[t+s]); __syncthreads(); }
        const float mx = red[0];
        __syncthreads();
        float lsum = 0.f;
        #pragma unroll
        for (int k = 0; k < 4; ++k) {
            float4 vv = v4[k];
            vv.x = __expf(vv.x - mx); vv.y = __expf(vv.y - mx);
            vv.z = __expf(vv.z - mx); vv.w = __expf(vv.w - mx);
            v4[k] = vv;
            lsum += vv.x + vv.y + vv.z + vv.w;
        }
        red[t] = lsum; __syncthreads();
        for (int s = 128; s > 0; s >>= 1) { if (t < s) red[t] += red[t+s]; __syncthreads(); }
        const float inv = 1.0f / red[0];
        __syncthreads();
        #pragma unroll
        for (int k = 0; k < 4; ++k) {
            float4 vv = v4[k];
            vv.x *= inv; vv.y *= inv; vv.z *= inv; vv.w *= inv;
            ((float4*)pl)[k * 256 + t] = vv;
            ((float4*)dst)[k * 256 + t] = vv;
        }
        __syncthreads();
    }

    // m_h: thread (chunk=t>>6, d=t&63); p broadcast from LDS, vals coalesced
    const int ch = t >> 6, d = t & 63;
    const float* vb = vals + (size_t)b * 4096 * 64 + d;
    float acc0 = 0.f, acc1 = 0.f;
    const int x0 = ch * 1024;
    for (int x = x0; x < x0 + 1024; ++x) {
        const float vvv = vb[(size_t)x * 64];
        acc0 += p0[x] * vvv;
        acc1 += p1[x] * vvv;
    }
    for (int rr = 0; rr < 2; ++rr) {
        mpart[ch][d] = rr ? acc1 : acc0;
        __syncthreads();
        if (t < 64) {
            const float m = mpart[0][t] + mpart[1][t] + mpart[2][t] + mpart[3][t];
            mh[(size_t)(row0 + rr) * 64 + t] = m;
        }
        __syncthreads();
    }
}

// ---------------------------------------------------------------------------
// Kernel 5: hyperbolic epilogue -> curr_hyp[b][64]
// ---------------------------------------------------------------------------
__global__ __launch_bounds__(64) void k_final(
    const float* __restrict__ mh, float* __restrict__ out)
{
    const int b = blockIdx.x;
    const int d = threadIdx.x;
    float accO = 0.f;
    for (int a = 0; a < 16; ++a) {
        float accY = 0.f;
        for (int h = 0; h < 8; ++h) {
            const float m = mh[(size_t)((b*8 + h) * 16 + a) * 64 + d];
            float ss = m * m;
            #pragma unroll
            for (int msk = 32; msk > 0; msk >>= 1) ss += __shfl_xor(ss, msk, 64);
            const float nm = sqrtf(ss);
            const float n1 = fmaxf(nm, 1e-15f);
            const float t1 = tanhf(n1);
            const float e  = t1 * m / n1;
            const float ne = t1 * nm / n1;
            const float n2 = fmaxf(ne, 1e-15f);
            const float u  = fminf(n2, 1.0f - 1e-5f);
            accY += atanhf(u) * e / n2;
        }
        const float ym = accY * 0.125f;
        float ssy = ym * ym;
        #pragma unroll
        for (int msk = 32; msk > 0; msk >>= 1) ssy += __shfl_xor(ssy, msk, 64);
        const float nmy = sqrtf(ssy);
        const float n3 = fmaxf(nmy, 1e-15f);
        const float t3 = tanhf(n3);
        const float chv = t3 * ym / n3;
        const float nch = t3 * nmy / n3;
        const float nrm = fmaxf(nch, 1e-6f);
        const float sc = fminf((1.0f - 1e-5f) / nrm, 1.0f);
        accO += chv * sc;
    }
    out[b * 64 + d] = accO * (1.0f / 16.0f);
}

// ---------------------------------------------------------------------------
extern "C" void kernel_launch(void* const* d_in, const int* in_sizes, int n_in,
                              void* d_out, int out_size, void* d_ws, size_t ws_size,
                              hipStream_t stream) {
    const float* curr_rho  = (const float*)d_in[0];
    const float* demo_rho  = (const float*)d_in[1];
    const float* demo_hyp  = (const float*)d_in[2];
    const int*   demo_mask = (const int*)d_in[3];
    const float* Wq   = (const float*)d_in[4];
    const float* Wk   = (const float*)d_in[5];
    const float* lnqw = (const float*)d_in[6];
    const float* lnqb = (const float*)d_in[7];
    const float* lnkw = (const float*)d_in[8];
    const float* lnkb = (const float*)d_in[9];

    float* out  = (float*)d_out;
    float* attn = out + 256;                 // curr_hyp first (B*DH=256), then attn

    float* ws   = (float*)d_ws;
    float* g    = ws;                        // 131072 floats
    float* s0   = ws + 131072;               // 512
    float* s2   = ws + 131584;               // 512
    float* vals = ws + 132096;               // 1048576
    float* mh   = ws + 1180672;              // 32768

    hipLaunchKernelGGL(k_prep, dim3(64), dim3(256), 0, stream,
                       curr_rho, Wq, Wk, lnqw, lnqb, lnkw, lnkb, g, s0, s2);
    hipLaunchKernelGGL(k_vals, dim3(4096), dim3(256), 0, stream, demo_hyp, vals);
    hipLaunchKernelGGL(k_scores, dim3(2048), dim3(256), 0, stream,
                       demo_rho, demo_mask, g, s0, s2, attn);
    hipLaunchKernelGGL(k_softmax_mh, dim3(256), dim3(256), 0, stream, attn, vals, mh);
    hipLaunchKernelGGL(k_final, dim3(4), dim3(64), 0, stream, mh, out);
}

// Round 3
// 458.712 us; speedup vs baseline: 1.2825x; 1.2825x over previous
//
#include <hip/hip_runtime.h>
#include <math.h>

#define LN_EPS_ 1e-5f
#define INV_SQRT_DHEAD 0.17677669529663687f  // 1/sqrt(32)

// B=4, A=16, N=8, L=512, DE=256, DH=64, H=8, DHEAD=32, NL=4096

__device__ __forceinline__ float waveReduceSum(float v) {
    #pragma unroll
    for (int m = 32; m > 0; m >>= 1) v += __shfl_xor(v, m, 64);
    return v;
}
__device__ __forceinline__ float waveReduceMax(float v) {
    #pragma unroll
    for (int m = 32; m > 0; m >>= 1) v = fmaxf(v, __shfl_xor(v, m, 64));
    return v;
}

// ---------------------------------------------------------------------------
// Kernel 1: per (b,a): q = LN(curr_rho) @ Wq.T ; qk[h,e] = sum_dh q[h*32+dh]*Wk[h*32+dh,e]
// g[b,a,h,e] = ln_k_w[e]*qk ; s0 = sum_e g ; s2 = sum_e ln_k_b[e]*qk
// ---------------------------------------------------------------------------
__global__ __launch_bounds__(256) void k_prep(
    const float* __restrict__ curr_rho, const float* __restrict__ Wq,
    const float* __restrict__ Wk, const float* __restrict__ lnqw,
    const float* __restrict__ lnqb, const float* __restrict__ lnkw,
    const float* __restrict__ lnkb,
    float* __restrict__ g, float* __restrict__ s0, float* __restrict__ s2)
{
    __shared__ float xs[256];
    __shared__ float qs[256];
    __shared__ float red[8];
    const int t = threadIdx.x;
    const int w = t >> 6;
    const int ba = blockIdx.x;  // b*16+a
    const float x = curr_rho[(size_t)ba * 256 + t];

    float sm = waveReduceSum(x);
    if ((t & 63) == 0) red[w] = sm;
    __syncthreads();
    const float mu = (red[0] + red[1] + red[2] + red[3]) * (1.0f / 256.0f);
    __syncthreads();
    const float dx = x - mu;
    float sq = waveReduceSum(dx * dx);
    if ((t & 63) == 0) red[w] = sq;
    __syncthreads();
    const float var = (red[0] + red[1] + red[2] + red[3]) * (1.0f / 256.0f);
    const float rstd = 1.0f / sqrtf(var + LN_EPS_);
    __syncthreads();
    xs[t] = dx * rstd * lnqw[t] + lnqb[t];
    __syncthreads();

    // q[t] = dot(xs, Wq[t,:])
    {
        const float4* wq4 = (const float4*)(Wq + (size_t)t * 256);
        float acc = 0.f;
        #pragma unroll 8
        for (int e4 = 0; e4 < 64; ++e4) {
            float4 wv = wq4[e4];
            acc += xs[e4*4+0]*wv.x + xs[e4*4+1]*wv.y + xs[e4*4+2]*wv.z + xs[e4*4+3]*wv.w;
        }
        qs[t] = acc;
    }
    __syncthreads();

    for (int h = 0; h < 8; ++h) {
        float qk = 0.f;
        #pragma unroll 8
        for (int dh = 0; dh < 32; ++dh)
            qk += qs[h*32+dh] * Wk[(size_t)(h*32+dh)*256 + t];
        const float gv = lnkw[t] * qk;
        const float b2 = lnkb[t] * qk;
        g[((size_t)ba * 8 + h) * 256 + t] = gv;
        float sg = waveReduceSum(gv);
        float sb = waveReduceSum(b2);
        if ((t & 63) == 0) { red[w] = sg; red[4 + w] = sb; }
        __syncthreads();
        if (t == 0) {
            s0[ba*8+h] = red[0] + red[1] + red[2] + red[3];
            s2[ba*8+h] = red[4] + red[5] + red[6] + red[7];
        }
        __syncthreads();
    }
}

// ---------------------------------------------------------------------------
// Kernel 2: vals_tan0 = logmap0(demo_hyp)  (rows of 64; one wave per row)
// ---------------------------------------------------------------------------
__global__ __launch_bounds__(256) void k_vals(
    const float* __restrict__ demo_hyp, float* __restrict__ vals)
{
    const int t = threadIdx.x;
    const size_t idx = (size_t)blockIdx.x * 256 + t;
    const float x = demo_hyp[idx];
    const float ss = waveReduceSum(x * x);
    const float nrm = sqrtf(ss);
    const float n = fmaxf(nrm, 1e-15f);
    const float u = fminf(n, 1.0f - 1e-5f);
    const float f = atanhf(u) / n;
    vals[idx] = x * f;
}

// ---------------------------------------------------------------------------
// Kernel 3 (the streamer): scores[b,h,a,n,l] = (rstd*(S1 - mu*s0) + s2)/sqrt(32)
// Block = (b, a, n, 128 l's). 256 thr: half-wave (32 lanes) per row, 8 floats/lane.
// All reductions are in-wave shuffle butterflies -> zero barriers in the p-loop,
// so demo_rho loads pipeline across passes.
// ---------------------------------------------------------------------------
__global__ __launch_bounds__(256) void k_scores(
    const float* __restrict__ demo_rho, const int* __restrict__ demo_mask,
    const float* __restrict__ g, const float* __restrict__ s0,
    const float* __restrict__ s2, float* __restrict__ attn)
{
    __shared__ float sbuf[8][132];
    const int t = threadIdx.x;
    const int gid = blockIdx.x;
    const int lc = gid & 3;
    const int n  = (gid >> 2) & 7;
    const int a  = (gid >> 5) & 15;
    const int b  = gid >> 9;
    const int c  = t & 31;   // column group (8 floats each)
    const int r  = t >> 5;   // row within pass (0..7)

    // g fragments -> registers (64 floats/lane)
    float gr[8][8];
    {
        const float* gb = g + ((size_t)(b*16 + a) * 8) * 256 + c * 8;
        #pragma unroll
        for (int h = 0; h < 8; ++h) {
            float4 ga = *(const float4*)(gb + h * 256);
            float4 gc = *(const float4*)(gb + h * 256 + 4);
            gr[h][0]=ga.x; gr[h][1]=ga.y; gr[h][2]=ga.z; gr[h][3]=ga.w;
            gr[h][4]=gc.x; gr[h][5]=gc.y; gr[h][6]=gc.z; gr[h][7]=gc.w;
        }
    }
    const float s0v = s0[(b*16 + a) * 8 + (c & 7)];
    const float s2v = s2[(b*16 + a) * 8 + (c & 7)];
    const int* mrow = demo_mask + (b*8 + n) * 512 + lc * 128;

    const float* xbase = demo_rho +
        ((size_t)((b*8 + n) * 512 + lc * 128) * 16 + a) * 256 + c * 8;

    #pragma unroll 2
    for (int p = 0; p < 16; ++p) {
        const float* xp = xbase + (size_t)(p * 8 + r) * 4096;  // row stride = A*DE
        float4 xa = *(const float4*)(xp);
        float4 xb = *(const float4*)(xp + 4);
        float xv[8] = {xa.x, xa.y, xa.z, xa.w, xb.x, xb.y, xb.z, xb.w};

        float v[10];
        #pragma unroll
        for (int h = 0; h < 8; ++h) {
            float acc = 0.f;
            #pragma unroll
            for (int j = 0; j < 8; ++j) acc += xv[j] * gr[h][j];
            v[h] = acc;
        }
        float sm = 0.f, sq = 0.f;
        #pragma unroll
        for (int j = 0; j < 8; ++j) { sm += xv[j]; sq += xv[j] * xv[j]; }
        v[8] = sm; v[9] = sq;

        // butterfly across the 32 lanes of this half-wave
        #pragma unroll
        for (int m = 1; m <= 16; m <<= 1) {
            #pragma unroll
            for (int i = 0; i < 10; ++i) v[i] += __shfl_xor(v[i], m, 32);
        }

        if (c < 8) {
            const float mu   = v[8] * (1.0f / 256.0f);
            const float var  = v[9] * (1.0f / 256.0f) - mu * mu;
            const float rstd = 1.0f / sqrtf(var + LN_EPS_);
            float sc = (rstd * (v[c] - mu * s0v) + s2v) * INV_SQRT_DHEAD;
            const int lidx = p * 8 + r;
            if (mrow[lidx] == 0) sc = -INFINITY;
            sbuf[c][lidx] = sc;
        }
    }
    __syncthreads();
    // coalesced write of the 8x128 score tile
    {
        const int h = t >> 5;
        const float* rowp = &sbuf[h][0];
        float4 vout = *(const float4*)(rowp + c * 4);
        const size_t off = (size_t)((b*8 + h) * 16 + a) * 4096 + n * 512 + lc * 128 + c * 4;
        *(float4*)(attn + off) = vout;
    }
}

// ---------------------------------------------------------------------------
// Kernel 4: softmax over 4096 per (b,h,a) row (2 rows/block) + m_h = attn @ vals
// ---------------------------------------------------------------------------
__global__ __launch_bounds__(256) void k_softmax_mh(
    float* __restrict__ attn, const float* __restrict__ vals,
    float* __restrict__ mh)
{
    __shared__ float p0[4096];
    __shared__ float p1[4096];
    __shared__ float red[4];
    __shared__ float mpart[4][64];
    const int t = threadIdx.x;
    const int w = t >> 6;
    const int row0 = blockIdx.x * 2;
    const int b = row0 >> 7;

    for (int rr = 0; rr < 2; ++rr) {
        const int row = row0 + rr;
        float* dst = attn + (size_t)row * 4096;
        float* pl = rr ? p1 : p0;
        float lmax = -INFINITY;
        float4 v4[4];
        #pragma unroll
        for (int k = 0; k < 4; ++k) {
            float4 vv = ((const float4*)dst)[k * 256 + t];
            v4[k] = vv;
            lmax = fmaxf(lmax, fmaxf(fmaxf(vv.x, vv.y), fmaxf(vv.z, vv.w)));
        }
        lmax = waveReduceMax(lmax);
        if ((t & 63) == 0) red[w] = lmax;
        __syncthreads();
        const float mx = fmaxf(fmaxf(red[0], red[1]), fmaxf(red[2], red[3]));
        __syncthreads();
        float lsum = 0.f;
        #pragma unroll
        for (int k = 0; k < 4; ++k) {
            float4 vv = v4[k];
            vv.x = __expf(vv.x - mx); vv.y = __expf(vv.y - mx);
            vv.z = __expf(vv.z - mx); vv.w = __expf(vv.w - mx);
            v4[k] = vv;
            lsum += vv.x + vv.y + vv.z + vv.w;
        }
        lsum = waveReduceSum(lsum);
        if ((t & 63) == 0) red[w] = lsum;
        __syncthreads();
        const float inv = 1.0f / (red[0] + red[1] + red[2] + red[3]);
        __syncthreads();
        #pragma unroll
        for (int k = 0; k < 4; ++k) {
            float4 vv = v4[k];
            vv.x *= inv; vv.y *= inv; vv.z *= inv; vv.w *= inv;
            ((float4*)pl)[k * 256 + t] = vv;
            ((float4*)dst)[k * 256 + t] = vv;
        }
    }
    __syncthreads();

    // m_h: thread (chunk=t>>6, d=t&63); p broadcast from LDS, vals coalesced
    const int ch = t >> 6, d = t & 63;
    const float* vb = vals + (size_t)b * 4096 * 64 + d;
    float acc0a = 0.f, acc0b = 0.f, acc1a = 0.f, acc1b = 0.f;
    const int x0 = ch * 1024;
    #pragma unroll 16
    for (int x = x0; x < x0 + 1024; x += 2) {
        const float va = vb[(size_t)x * 64];
        const float vc = vb[(size_t)(x + 1) * 64];
        acc0a += p0[x] * va;     acc0b += p0[x + 1] * vc;
        acc1a += p1[x] * va;     acc1b += p1[x + 1] * vc;
    }
    const float acc0 = acc0a + acc0b;
    const float acc1 = acc1a + acc1b;
    for (int rr = 0; rr < 2; ++rr) {
        mpart[ch][d] = rr ? acc1 : acc0;
        __syncthreads();
        if (t < 64) {
            const float m = mpart[0][t] + mpart[1][t] + mpart[2][t] + mpart[3][t];
            mh[(size_t)(row0 + rr) * 64 + t] = m;
        }
        __syncthreads();
    }
}

// ---------------------------------------------------------------------------
// Kernel 5: hyperbolic epilogue -> curr_hyp[b][64]; one wave per a (1024 thr!)
// ---------------------------------------------------------------------------
__global__ __launch_bounds__(1024) void k_final(
    const float* __restrict__ mh, float* __restrict__ out)
{
    __shared__ float contrib[16][64];
    const int t = threadIdx.x;
    const int a = t >> 6, d = t & 63;
    const int b = blockIdx.x;
    float accY = 0.f;
    #pragma unroll
    for (int h = 0; h < 8; ++h) {
        const float m = mh[(size_t)((b*8 + h) * 16 + a) * 64 + d];
        const float ss = waveReduceSum(m * m);
        const float nm = sqrtf(ss);
        const float n1 = fmaxf(nm, 1e-15f);
        const float t1 = tanhf(n1);
        const float e  = t1 * m / n1;
        const float ne = t1 * nm / n1;
        const float n2 = fmaxf(ne, 1e-15f);
        const float u  = fminf(n2, 1.0f - 1e-5f);
        accY += atanhf(u) * e / n2;
    }
    const float ym = accY * 0.125f;
    const float ssy = waveReduceSum(ym * ym);
    const float nmy = sqrtf(ssy);
    const float n3 = fmaxf(nmy, 1e-15f);
    const float t3 = tanhf(n3);
    const float chv = t3 * ym / n3;
    const float nch = t3 * nmy / n3;
    const float nrm = fmaxf(nch, 1e-6f);
    const float sc = fminf((1.0f - 1e-5f) / nrm, 1.0f);
    contrib[a][d] = chv * sc;
    __syncthreads();
    if (t < 64) {
        float s = 0.f;
        #pragma unroll
        for (int a2 = 0; a2 < 16; ++a2) s += contrib[a2][t];
        out[b * 64 + t] = s * (1.0f / 16.0f);
    }
}

// ---------------------------------------------------------------------------
extern "C" void kernel_launch(void* const* d_in, const int* in_sizes, int n_in,
                              void* d_out, int out_size, void* d_ws, size_t ws_size,
                              hipStream_t stream) {
    const float* curr_rho  = (const float*)d_in[0];
    const float* demo_rho  = (const float*)d_in[1];
    const float* demo_hyp  = (const float*)d_in[2];
    const int*   demo_mask = (const int*)d_in[3];
    const float* Wq   = (const float*)d_in[4];
    const float* Wk   = (const float*)d_in[5];
    const float* lnqw = (const float*)d_in[6];
    const float* lnqb = (const float*)d_in[7];
    const float* lnkw = (const float*)d_in[8];
    const float* lnkb = (const float*)d_in[9];

    float* out  = (float*)d_out;
    float* attn = out + 256;                 // curr_hyp first (B*DH=256), then attn

    float* ws   = (float*)d_ws;
    float* g    = ws;                        // 131072 floats
    float* s0   = ws + 131072;               // 512
    float* s2   = ws + 131584;               // 512
    float* vals = ws + 132096;               // 1048576
    float* mh   = ws + 1180672;              // 32768

    hipLaunchKernelGGL(k_prep, dim3(64), dim3(256), 0, stream,
                       curr_rho, Wq, Wk, lnqw, lnqb, lnkw, lnkb, g, s0, s2);
    hipLaunchKernelGGL(k_vals, dim3(4096), dim3(256), 0, stream, demo_hyp, vals);
    hipLaunchKernelGGL(k_scores, dim3(2048), dim3(256), 0, stream,
                       demo_rho, demo_mask, g, s0, s2, attn);
    hipLaunchKernelGGL(k_softmax_mh, dim3(256), dim3(256), 0, stream, attn, vals, mh);
    hipLaunchKernelGGL(k_final, dim3(4), dim3(1024), 0, stream, mh, out);
}